// Round 11
// baseline (78.634 us; speedup 1.0000x reference)
//
#include <hip/hip_runtime.h>

#define NUM_V 100000
#define NUM_R 1000
#define ARITY 3
#define DD 128
#define DI 192   /* D + I */
#define HH 128
#define BB 4096
#define NN 64

typedef __attribute__((ext_vector_type(4))) float f32x4;
typedef __attribute__((ext_vector_type(8))) _Float16 half8;
typedef __attribute__((ext_vector_type(2))) _Float16 half2v;

// async global->LDS, 16B per lane; LDS dest is wave-uniform base, HW adds lane*16
__device__ inline void gload16(const void* g, void* lds) {
    __builtin_amdgcn_global_load_lds(
        (const __attribute__((address_space(1))) unsigned int*)g,
        (__attribute__((address_space(3))) unsigned int*)lds, 16, 0, 0);
}

// ---------------- Fused prep: proj(R) | wfrag(WV, f16) | pe ------------------
// blocks 0..31  : proj body (RWh = R @ WR + bR -> fp16)
// blocks 32..79 : wfrag body (f16 W fragments, MFMA layout, single table)
// block  80     : peProd[h] = prod_a (P[a]@WP + bP)[h]
__global__ __launch_bounds__(256) void prep_kernel(
    const float* __restrict__ R, const float* __restrict__ WR, const float* __restrict__ bR,
    _Float16* __restrict__ RWh,
    const float* __restrict__ WV, unsigned short* __restrict__ wf,
    const float* __restrict__ P, const float* __restrict__ WP, const float* __restrict__ bP,
    float* __restrict__ peProd) {
    const int bid = blockIdx.x;
    const int tid = threadIdx.x;

    if (bid < 32) {
        const int lane = tid & 63;
        const int wave = tid >> 6;
        const int wavesPerGrid = 32 * 4;
        const int waveId = bid * 4 + wave;
        const float2 b2 = ((const float2*)bR)[lane];
        const float2* __restrict__ W2 = (const float2*)WR;
        for (int rowBase0 = waveId * 8; rowBase0 < NUM_R; rowBase0 += wavesPerGrid * 8) {
            const int rowBase = __builtin_amdgcn_readfirstlane(rowBase0);
            float2 acc[8];
#pragma unroll
            for (int r8 = 0; r8 < 8; ++r8) acc[r8] = make_float2(0.f, 0.f);
#pragma unroll 4
            for (int k4 = 0; k4 < DD / 4; ++k4) {
                float4 v[8];
#pragma unroll
                for (int r8 = 0; r8 < 8; ++r8)
                    v[r8] = ((const float4*)(R + (size_t)(rowBase + r8) * DD))[k4];
#pragma unroll
                for (int kk = 0; kk < 4; ++kk) {
                    float2 w = W2[(k4 * 4 + kk) * 64 + lane];
#pragma unroll
                    for (int r8 = 0; r8 < 8; ++r8) {
                        float vv = (kk == 0) ? v[r8].x : (kk == 1) ? v[r8].y : (kk == 2) ? v[r8].z : v[r8].w;
                        acc[r8].x += vv * w.x;
                        acc[r8].y += vv * w.y;
                    }
                }
            }
#pragma unroll
            for (int r8 = 0; r8 < 8; ++r8) {
                if (rowBase + r8 < NUM_R) {
                    half2v h;
                    h.x = (_Float16)(acc[r8].x + b2.x);
                    h.y = (_Float16)(acc[r8].y + b2.y);
                    *(half2v*)(RWh + (size_t)(rowBase + r8) * HH + lane * 2) = h;
                }
            }
        }
    } else if (bid < 80) {
        // ---- wfrag (f16): wf[kstep(6)][ctile(8)][lane(64)][j(8)] ushort(f16 bits)
        if (tid < 64) {
            const int wb = bid - 32;
            const int ks = wb >> 3;  // 0..5
            const int ct = wb & 7;   // 0..7
            const int l = tid;       // 0..63
            const int col = ct * 16 + (l & 15);
            const int k0 = ks * 32 + (l >> 4) * 8;
            size_t base = (size_t)(ks * 8 + ct) * 512;
#pragma unroll
            for (int j = 0; j < 8; ++j) {
                float v = WV[(size_t)(k0 + j) * HH + col];
                wf[base + l * 8 + j] = __builtin_bit_cast(unsigned short, (_Float16)v);
            }
        }
    } else {
        if (tid < HH) {
            int h = tid;
            float prod = 1.0f;
            for (int a = 0; a < ARITY; ++a) {
                float acc = bP[h];
                for (int d = 0; d < DD; ++d) acc += P[a * DD + d] * WP[d * HH + h];
                prod *= acc;
            }
            peProd[h] = prod;
        }
    }
}

// ---------------- B-resident f16 GEMM, non-temporal streaming ----------------
// C(fp16) = A @ W + bias. Single-variable experiment on the 11-round ~2.2 TB/s
// service-rate invariant (choreography / occupancy / burst-density / wave-count
// / issue-weight all falsified): A is touched ONCE (zero reuse) yet allocates
// through the 4 MB/XCD L2, evicting constantly; dirty C-lines evict interleaved
// with A-fills -> fine-grained HBM read/write turnaround + L2 tag churn. Fix:
// `nt`-flagged A-loads (__builtin_nontemporal_load) and C-stores
// (__builtin_nontemporal_store) -- no L2 allocation for the streams. Structure
// otherwise byte-identical to round 10: W table (48 KB f16) LDS-resident, one
// barrier, 16-row tiles, 6250 streaming waves (26/CU), 3-deep A prefetch.
__global__ __launch_bounds__(832, 6) void gemm_bres(const float* __restrict__ A,
                                                    const unsigned short* __restrict__ wf,
                                                    const float* __restrict__ bias,
                                                    _Float16* __restrict__ C, int M) {
    __shared__ unsigned short bsm[24576];  // 48 KB, byte-identical to wfrag layout

    const int tid = threadIdx.x;
    const int l = tid & 63;
    const int wv = tid >> 6;  // 0..12

    const int tile = wv * 512 + blockIdx.x;  // 0..6655, each hit exactly once
    const int rowbase = tile * 16;
    const bool active = rowbase < M;  // wave-uniform (M = 6250*16 exactly)

    // bias per col-tile
    float bcol[8];
#pragma unroll
    for (int ct = 0; ct < 8; ++ct) bcol[ct] = bias[ct * 16 + (l & 15)];

    // A fragment pointer: row = rowbase + (l&15), k-base (l>>4)*8
    const float* aptr;
    {
        int rr = rowbase + (l & 15);
        if (rr >= M) rr = M - 1;
        aptr = A + (size_t)rr * DI + (l >> 4) * 8;
    }

    f32x4 acc[8];
#pragma unroll
    for (int ct = 0; ct < 8; ++ct) acc[ct] = (f32x4){0.f, 0.f, 0.f, 0.f};

    f32x4 va[3][2];  // [buf][half] -- 3-deep pipeline, static indices
#define LOAD_A(buf, ks)                                                          \
    do {                                                                         \
        va[buf][0] = __builtin_nontemporal_load((const f32x4*)(aptr + (ks) * 32)); \
        va[buf][1] = __builtin_nontemporal_load((const f32x4*)(aptr + (ks) * 32 + 4)); \
    } while (0)

    // prologue A loads first (start HBM/L3 traffic earliest)
    if (active) {
        LOAD_A(0, 0);
        LOAD_A(1, 1);
    }

    // ---- stage f16 W table: waves 0..11 stage 4 KB each = 48 KB, linear
    if (wv < 12) {
#pragma unroll
        for (int i = 0; i < 4; ++i) {
            const int off = wv * 4096 + i * 1024;  // bytes, wave-uniform dest
            gload16((const char*)wf + off + l * 16, (char*)bsm + off);
        }
    }

    __syncthreads();  // the ONLY barrier: publishes LDS W-table to all waves
    if (!active) return;

#pragma unroll
    for (int ks = 0; ks < 6; ++ks) {
        const int cur = ks % 3;
        if (ks < 4) LOAD_A((ks + 2) % 3, ks + 2);

        // fp32 -> f16 convert of current A fragment (8 v_cvt, RNE)
        half8 ah;
        {
            half8 t;
            t[0] = (_Float16)va[cur][0].x;
            t[1] = (_Float16)va[cur][0].y;
            t[2] = (_Float16)va[cur][0].z;
            t[3] = (_Float16)va[cur][0].w;
            t[4] = (_Float16)va[cur][1].x;
            t[5] = (_Float16)va[cur][1].y;
            t[6] = (_Float16)va[cur][1].z;
            t[7] = (_Float16)va[cur][1].w;
            ah = t;
        }

#pragma unroll
        for (int ct = 0; ct < 8; ++ct) {
            const int fb = (ks * 8 + ct) * 512;  // ushort index of fragment
            half8 bh = *(const half8*)&bsm[fb + l * 8];
            acc[ct] = __builtin_amdgcn_mfma_f32_16x16x32_f16(ah, bh, acc[ct], 0, 0, 0);
        }
    }
#undef LOAD_A

    // epilogue: wave writes full 256B C-lines (col = ct*16 + (l&15)), nt stores
    {
        const int rb = rowbase + (l >> 4) * 4;
#pragma unroll
        for (int j = 0; j < 4; ++j) {
            const int row = rb + j;
            if (row < M) {
#pragma unroll
                for (int ct = 0; ct < 8; ++ct)
                    __builtin_nontemporal_store((_Float16)(acc[ct][j] + bcol[ct]),
                                                &C[(size_t)row * HH + ct * 16 + (l & 15)]);
            }
        }
    }
}

// ---------------- Gather - product - neighbor-sum (fp16 tables) --------------
// out[b,h] = peProd[h] * sum_n RWh[r[b,n]][h] * prod_a VWh[e[a,b,n]][h]
__global__ __launch_bounds__(256) void gather_kernel(const int* __restrict__ r,
                                                     const int* __restrict__ e,
                                                     const _Float16* __restrict__ VWh,
                                                     const _Float16* __restrict__ RWh,
                                                     const float* __restrict__ peProd,
                                                     float* __restrict__ out) {
    __shared__ int rIdx[NN];
    __shared__ int eIdx[ARITY][NN];
    __shared__ float4 partial[3][16][2];

    const int b = blockIdx.x;
    const int tid = threadIdx.x;

    if (tid < NN) {
        rIdx[tid] = r[b * NN + tid];
    } else {
        int t = tid - NN;
        eIdx[t >> 6][t & 63] = e[(size_t)(t >> 6) * BB * NN + b * NN + (t & 63)];
    }
    __syncthreads();

    const int lane = tid & 63;
    const int wv = tid >> 6;    // 0..3
    const int q = lane >> 4;    // neighbor sub-slot 0..3
    const int ho = lane & 15;   // h-octet: h = ho*8 .. +8

    float acc8[8];
#pragma unroll
    for (int k = 0; k < 8; ++k) acc8[k] = 0.f;

#pragma unroll
    for (int it = 0; it < 4; ++it) {
        int n = it * 16 + wv * 4 + q;
        half8 rw = *(const half8*)(RWh + (size_t)rIdx[n] * HH + ho * 8);
        half8 v0 = *(const half8*)(VWh + (size_t)eIdx[0][n] * HH + ho * 8);
        half8 v1 = *(const half8*)(VWh + (size_t)eIdx[1][n] * HH + ho * 8);
        half8 v2 = *(const half8*)(VWh + (size_t)eIdx[2][n] * HH + ho * 8);
        half8 p = rw * v0;
        p = p * v1;
        p = p * v2;
#pragma unroll
        for (int k = 0; k < 8; ++k) acc8[k] += (float)p[k];
    }

    // combine the 4 neighbor sub-slots (lane quarters share ho)
#pragma unroll
    for (int k = 0; k < 8; ++k) {
        acc8[k] += __shfl_xor(acc8[k], 16);
        acc8[k] += __shfl_xor(acc8[k], 32);
    }

    if (wv > 0 && lane < 16) {
        partial[wv - 1][ho][0] = make_float4(acc8[0], acc8[1], acc8[2], acc8[3]);
        partial[wv - 1][ho][1] = make_float4(acc8[4], acc8[5], acc8[6], acc8[7]);
    }
    __syncthreads();
    if (wv == 0 && lane < 16) {
        float4 s0 = make_float4(acc8[0], acc8[1], acc8[2], acc8[3]);
        float4 s1 = make_float4(acc8[4], acc8[5], acc8[6], acc8[7]);
#pragma unroll
        for (int g = 0; g < 3; ++g) {
            float4 t0 = partial[g][ho][0], t1 = partial[g][ho][1];
            s0.x += t0.x; s0.y += t0.y; s0.z += t0.z; s0.w += t0.w;
            s1.x += t1.x; s1.y += t1.y; s1.z += t1.z; s1.w += t1.w;
        }
        float4 p0 = ((const float4*)peProd)[ho * 2];
        float4 p1 = ((const float4*)peProd)[ho * 2 + 1];
        ((float4*)(out + (size_t)b * HH))[ho * 2] =
            make_float4(s0.x * p0.x, s0.y * p0.y, s0.z * p0.z, s0.w * p0.w);
        ((float4*)(out + (size_t)b * HH))[ho * 2 + 1] =
            make_float4(s1.x * p1.x, s1.y * p1.y, s1.z * p1.z, s1.w * p1.w);
    }
}

// ---------------- Launch -----------------------------------------------------
extern "C" void kernel_launch(void* const* d_in, const int* in_sizes, int n_in,
                              void* d_out, int out_size, void* d_ws, size_t ws_size,
                              hipStream_t stream) {
    const int* r = (const int*)d_in[0];
    const int* e = (const int*)d_in[1];
    const float* V = (const float*)d_in[2];
    const float* R = (const float*)d_in[3];
    const float* P = (const float*)d_in[4];
    const float* WV = (const float*)d_in[5];
    const float* bV = (const float*)d_in[6];
    const float* WR = (const float*)d_in[7];
    const float* bR = (const float*)d_in[8];
    const float* WP = (const float*)d_in[9];
    const float* bP = (const float*)d_in[10];
    float* out = (float*)d_out;

    // ws layout: VWh [NUM_V,H] fp16 | RWh [NUM_R,H] fp16 | peProd [H] f32 | Wfrag 48 KB (f16)
    _Float16* VWh = (_Float16*)d_ws;
    _Float16* RWh = VWh + (size_t)NUM_V * HH;
    float* peProd = (float*)(RWh + (size_t)NUM_R * HH);
    unsigned short* wfrag = (unsigned short*)(peProd + HH);

    prep_kernel<<<81, 256, 0, stream>>>(R, WR, bR, RWh, WV, wfrag, P, WP, bP, peProd);
    gemm_bres<<<512, 832, 0, stream>>>(V, wfrag, bV, VWh, NUM_V);
    gather_kernel<<<BB, 256, 0, stream>>>(r, e, VWh, RWh, peProd, out);
}

// Round 12
// 60.151 us; speedup vs baseline: 1.3073x; 1.3073x over previous
//
#include <hip/hip_runtime.h>

#define NUM_V 100000
#define NUM_R 1000
#define ARITY 3
#define DD 128
#define DI 192   /* D + I */
#define HH 128
#define BB 4096
#define NN 64

typedef __attribute__((ext_vector_type(4))) float f32x4;
typedef __attribute__((ext_vector_type(8))) _Float16 half8;
typedef __attribute__((ext_vector_type(2))) _Float16 half2v;

// ---------------- Fused GEMM + prep ------------------------------------------
// One kernel produces everything gather needs:
//   VWh = f16(V @ WV + bV)   -- MFMA path (R10 structure, unchanged)
//   RWh = f16(R @ WR + bR)   -- 2 rows/block, blocks 0..499, after epilogue
//   peProd[h] = prod_a (P[a]@WP+bP)[h]  -- block 511, after epilogue
// B-table (48 KB f16 MFMA fragments) is built IN-LDS per block from WV
// (98 KB, L2-hot), replacing the separate wfrag kernel + dependency; the
// build overlaps the prologue A-loads' HBM latency. GEMM core is byte-
// identical to round 10 (best: 68.7 us): 16-row tiles, 6250 streaming waves
// (26/CU), one barrier, 3-deep A register prefetch, f16 MFMA.
// Round-11 lesson (reverted): nt loads/stores on the streams REGRESSED
// (scalar fp16 nt stores break L2 write-combining) -- normal loads/stores.
__global__ __launch_bounds__(832, 6) void gemm_fused(
    const float* __restrict__ A, const float* __restrict__ WV, const float* __restrict__ bV,
    const float* __restrict__ R, const float* __restrict__ WR, const float* __restrict__ bR,
    const float* __restrict__ P, const float* __restrict__ WP, const float* __restrict__ bP,
    _Float16* __restrict__ VWh, _Float16* __restrict__ RWh, float* __restrict__ peProd,
    int M) {
    __shared__ unsigned short bsm[24576];  // 48 KB f16 B-table, wfrag layout

    const int tid = threadIdx.x;
    const int l = tid & 63;
    const int wv = tid >> 6;  // 0..12
    const int bid = blockIdx.x;

    const int tile = wv * 512 + bid;  // 0..6655, each hit exactly once
    const int rowbase = tile * 16;
    const bool active = rowbase < M;  // wave-uniform (M = 6250*16 exactly)

    // bias per col-tile
    float bcol[8];
#pragma unroll
    for (int ct = 0; ct < 8; ++ct) bcol[ct] = bV[ct * 16 + (l & 15)];

    // A fragment pointer: row = rowbase + (l&15), k-base (l>>4)*8
    const float* aptr;
    {
        int rr = rowbase + (l & 15);
        if (rr >= M) rr = M - 1;
        aptr = A + (size_t)rr * DI + (l >> 4) * 8;
    }

    f32x4 acc[8];
#pragma unroll
    for (int ct = 0; ct < 8; ++ct) acc[ct] = (f32x4){0.f, 0.f, 0.f, 0.f};

    float4 va[3][2];  // [buf][half] -- 3-deep pipeline, static indices
#define LOAD_A(buf, ks)                                      \
    do {                                                     \
        va[buf][0] = *(const float4*)(aptr + (ks) * 32);     \
        va[buf][1] = *(const float4*)(aptr + (ks) * 32 + 4); \
    } while (0)

    // prologue A loads first (start HBM traffic at t=0)
    if (active) {
        LOAD_A(0, 0);
        LOAD_A(1, 1);
    }

    // ---- build f16 B-table in LDS from WV (L2-hot; overlaps A latency) ----
    // ushort idx = (ks*8+ct)*512 + lane*8 + j  holds f16(WV[k][col]) with
    // k = ks*32+(lane>>4)*8+j, col = ct*16+(lane&15)  (== old wfrag layout).
    if (tid < 768) {
#pragma unroll
        for (int i = 0; i < 4; ++i) {
            const int g = i * 768 + tid;          // group 0..3071 (8 ushorts each)
            const int ks = g >> 9;                // 0..5
            const int ct = (g >> 6) & 7;          // 0..7
            const int ln = g & 63;                // fragment lane
            const int col = ct * 16 + (ln & 15);
            const int kbase = ks * 32 + ((ln >> 4) << 3);
            half8 hv;
#pragma unroll
            for (int j = 0; j < 8; ++j)
                hv[j] = (_Float16)WV[(size_t)(kbase + j) * HH + col];
            *(half8*)&bsm[(size_t)g * 8] = hv;
        }
    }

    __syncthreads();  // the ONLY barrier: publishes the LDS B-table

    if (active) {
#pragma unroll
        for (int ks = 0; ks < 6; ++ks) {
            const int cur = ks % 3;
            if (ks < 4) LOAD_A((ks + 2) % 3, ks + 2);

            // fp32 -> f16 convert of current A fragment (8 v_cvt, RNE)
            half8 ah;
            {
                half8 t;
                t[0] = (_Float16)va[cur][0].x;
                t[1] = (_Float16)va[cur][0].y;
                t[2] = (_Float16)va[cur][0].z;
                t[3] = (_Float16)va[cur][0].w;
                t[4] = (_Float16)va[cur][1].x;
                t[5] = (_Float16)va[cur][1].y;
                t[6] = (_Float16)va[cur][1].z;
                t[7] = (_Float16)va[cur][1].w;
                ah = t;
            }

#pragma unroll
            for (int ct = 0; ct < 8; ++ct) {
                const int fb = (ks * 8 + ct) * 512;  // ushort index of fragment
                half8 bh = *(const half8*)&bsm[fb + l * 8];
                acc[ct] = __builtin_amdgcn_mfma_f32_16x16x32_f16(ah, bh, acc[ct], 0, 0, 0);
            }
        }

        // epilogue: wave writes full 256B C-lines (col = ct*16 + (l&15))
        const int rb = rowbase + (l >> 4) * 4;
#pragma unroll
        for (int j = 0; j < 4; ++j) {
            const int row = rb + j;
            if (row < M) {
#pragma unroll
                for (int ct = 0; ct < 8; ++ct)
                    VWh[(size_t)row * HH + ct * 16 + (l & 15)] = (_Float16)(acc[ct][j] + bcol[ct]);
            }
        }
    }
#undef LOAD_A

    // ---- fused prep work (fills the block drain-tail; no barrier needed) ----
    if (bid < 500) {
        // proj: RWh rows bid*2, bid*2+1 (500*2 = 1000 = NUM_R exactly)
        if (tid < 256) {
            const int row = bid * 2 + (tid >> 7);
            const int col = tid & 127;
            float a2 = bR[col];
            const float* Rr = R + (size_t)row * DD;
            for (int d = 0; d < DD; ++d) a2 += Rr[d] * WR[(size_t)d * HH + col];
            RWh[(size_t)row * HH + col] = (_Float16)a2;
        }
    } else if (bid == 511) {
        // pe: peProd[h] = prod_a (P[a]@WP + bP)[h]
        if (tid < HH) {
            const int h = tid;
            float prod = 1.0f;
            for (int a = 0; a < ARITY; ++a) {
                float a2 = bP[h];
                for (int d = 0; d < DD; ++d) a2 += P[a * DD + d] * WP[d * HH + h];
                prod *= a2;
            }
            peProd[h] = prod;
        }
    }
}

// ---------------- Gather - product - neighbor-sum (fp16 tables) --------------
// out[b,h] = peProd[h] * sum_n RWh[r[b,n]][h] * prod_a VWh[e[a,b,n]][h]
__global__ __launch_bounds__(256) void gather_kernel(const int* __restrict__ r,
                                                     const int* __restrict__ e,
                                                     const _Float16* __restrict__ VWh,
                                                     const _Float16* __restrict__ RWh,
                                                     const float* __restrict__ peProd,
                                                     float* __restrict__ out) {
    __shared__ int rIdx[NN];
    __shared__ int eIdx[ARITY][NN];
    __shared__ float4 partial[3][16][2];

    const int b = blockIdx.x;
    const int tid = threadIdx.x;

    if (tid < NN) {
        rIdx[tid] = r[b * NN + tid];
    } else {
        int t = tid - NN;
        eIdx[t >> 6][t & 63] = e[(size_t)(t >> 6) * BB * NN + b * NN + (t & 63)];
    }
    __syncthreads();

    const int lane = tid & 63;
    const int wv = tid >> 6;    // 0..3
    const int q = lane >> 4;    // neighbor sub-slot 0..3
    const int ho = lane & 15;   // h-octet: h = ho*8 .. +8

    float acc8[8];
#pragma unroll
    for (int k = 0; k < 8; ++k) acc8[k] = 0.f;

#pragma unroll
    for (int it = 0; it < 4; ++it) {
        int n = it * 16 + wv * 4 + q;
        half8 rw = *(const half8*)(RWh + (size_t)rIdx[n] * HH + ho * 8);
        half8 v0 = *(const half8*)(VWh + (size_t)eIdx[0][n] * HH + ho * 8);
        half8 v1 = *(const half8*)(VWh + (size_t)eIdx[1][n] * HH + ho * 8);
        half8 v2 = *(const half8*)(VWh + (size_t)eIdx[2][n] * HH + ho * 8);
        half8 p = rw * v0;
        p = p * v1;
        p = p * v2;
#pragma unroll
        for (int k = 0; k < 8; ++k) acc8[k] += (float)p[k];
    }

    // combine the 4 neighbor sub-slots (lane quarters share ho)
#pragma unroll
    for (int k = 0; k < 8; ++k) {
        acc8[k] += __shfl_xor(acc8[k], 16);
        acc8[k] += __shfl_xor(acc8[k], 32);
    }

    if (wv > 0 && lane < 16) {
        partial[wv - 1][ho][0] = make_float4(acc8[0], acc8[1], acc8[2], acc8[3]);
        partial[wv - 1][ho][1] = make_float4(acc8[4], acc8[5], acc8[6], acc8[7]);
    }
    __syncthreads();
    if (wv == 0 && lane < 16) {
        float4 s0 = make_float4(acc8[0], acc8[1], acc8[2], acc8[3]);
        float4 s1 = make_float4(acc8[4], acc8[5], acc8[6], acc8[7]);
#pragma unroll
        for (int g = 0; g < 3; ++g) {
            float4 t0 = partial[g][ho][0], t1 = partial[g][ho][1];
            s0.x += t0.x; s0.y += t0.y; s0.z += t0.z; s0.w += t0.w;
            s1.x += t1.x; s1.y += t1.y; s1.z += t1.z; s1.w += t1.w;
        }
        float4 p0 = ((const float4*)peProd)[ho * 2];
        float4 p1 = ((const float4*)peProd)[ho * 2 + 1];
        ((float4*)(out + (size_t)b * HH))[ho * 2] =
            make_float4(s0.x * p0.x, s0.y * p0.y, s0.z * p0.z, s0.w * p0.w);
        ((float4*)(out + (size_t)b * HH))[ho * 2 + 1] =
            make_float4(s1.x * p1.x, s1.y * p1.y, s1.z * p1.z, s1.w * p1.w);
    }
}

// ---------------- Launch -----------------------------------------------------
extern "C" void kernel_launch(void* const* d_in, const int* in_sizes, int n_in,
                              void* d_out, int out_size, void* d_ws, size_t ws_size,
                              hipStream_t stream) {
    const int* r = (const int*)d_in[0];
    const int* e = (const int*)d_in[1];
    const float* V = (const float*)d_in[2];
    const float* R = (const float*)d_in[3];
    const float* P = (const float*)d_in[4];
    const float* WV = (const float*)d_in[5];
    const float* bV = (const float*)d_in[6];
    const float* WR = (const float*)d_in[7];
    const float* bR = (const float*)d_in[8];
    const float* WP = (const float*)d_in[9];
    const float* bP = (const float*)d_in[10];
    float* out = (float*)d_out;

    // ws layout: VWh [NUM_V,H] fp16 | RWh [NUM_R,H] fp16 | peProd [H] f32
    _Float16* VWh = (_Float16*)d_ws;
    _Float16* RWh = VWh + (size_t)NUM_V * HH;
    float* peProd = (float*)(RWh + (size_t)NUM_R * HH);

    gemm_fused<<<512, 832, 0, stream>>>(V, WV, bV, R, WR, bR, P, WP, bP,
                                        VWh, RWh, peProd, NUM_V);
    gather_kernel<<<BB, 256, 0, stream>>>(r, e, VWh, RWh, peProd, out);
}